// Round 7
// baseline (220.751 us; speedup 1.0000x reference)
//
#include <hip/hip_runtime.h>
#include <math.h>

#define NN      512     // N (columns of x)
#define KK      513     // K
#define BB      65536   // batch
#define TROWS   512     // table rows, t = 0..511
#define TCOLS   513     // table cols, g = 0..512
#define T16STR  528     // u32 stride per table row (2112 B, 64B-aligned)

#define RPB     64            // rows per tile
#define NSEG    8             // segments per row
#define SEGW    64            // columns per segment
#define BLK     (RPB * NSEG)  // 512 threads = 8 waves
#define XSTR    129           // LDS row stride in u32 (128 + 1 pad)
#define TPB2    2             // tiles per block (double-buffered pipeline)

typedef int iv4 __attribute__((ext_vector_type(4)));

__device__ __forceinline__ unsigned f2bf(float f) {   // RNE f32 -> bf16 (finite only)
    unsigned u = __float_as_uint(f);
    return (u + 0x7fffu + ((u >> 16) & 1u)) >> 16;
}

// T16[t*T16STR + g] = pack(bf16 logsm(c=0), bf16 logsm(c=1)); edges/unreachable = 0 (log 1)
__global__ void build_table_kernel(const float* __restrict__ W, unsigned* __restrict__ T16) {
    int idx = blockIdx.x * blockDim.x + threadIdx.x;
    if (idx >= TROWS * TCOLS) return;
    int t = idx / TCOLS;
    int g = idx - t * TCOLS;
    float v0 = 0.f, v1 = 0.f;
    if (t >= 1 && g >= 1 && g <= t) {
        const float* w = W + ((size_t)(t - 1) * (KK - 1) + (g - 1)) * 2;
        float w0 = w[0], w1 = w[1];
        float m  = fmaxf(w0, w1);
        float lse = m + logf(expf(w0 - m) + expf(w1 - m));
        v0 = w0 - lse;
        v1 = w1 - lse;
    }
    T16[t * T16STR + g] = f2bf(v0) | (f2bf(v1) << 16);
}

// logE[k] = endW[k] - logsumexp(endW)   (513 entries, f32), one wave
__global__ void build_endw_kernel(const float* __restrict__ endW, float* __restrict__ logE) {
    int lane = threadIdx.x;  // 0..63
    float vals[9];
    float m = -1e30f;
    #pragma unroll
    for (int k = 0; k < 9; ++k) {
        int i = lane + 64 * k;
        vals[k] = (i < KK) ? endW[i] : -1e30f;
        m = fmaxf(m, vals[k]);
    }
    #pragma unroll
    for (int d = 32; d >= 1; d >>= 1) m = fmaxf(m, __shfl_xor(m, d, 64));
    float s = 0.f;
    #pragma unroll
    for (int k = 0; k < 9; ++k) s += expf(vals[k] - m);
    #pragma unroll
    for (int d = 32; d >= 1; d >>= 1) s += __shfl_xor(s, d, 64);
    float lse = m + logf(s);
    #pragma unroll
    for (int k = 0; k < 9; ++k) {
        int i = lane + 64 * k;
        if (i < KK) logE[i] = endW[i] - lse;
    }
}

// Block = 512 threads = 8 waves; wave i = segment i of 64 rows.
// 2 tiles per block, double-buffered LDS: tile t+1's global loads are issued
// BEFORE tile t's gathers (HBM latency hidden under gather phase) and
// ds-written after them. Per tile:
//   read own-segment bytes from LDS -> popc -> segsum exchange -> prefix g ->
//   64 bf16-table gathers (one table row per wave-instruction, clustered g,
//   4B/entry -> minimal lines) -> per-row reduce + endW term.
__global__ __launch_bounds__(BLK, 4) void pc_main_kernel(
    const int* __restrict__ x, const unsigned* __restrict__ T16,
    const float* __restrict__ logE, float* __restrict__ out)
{
    __shared__ unsigned xb[2][RPB * XSTR];   // packed 0/1 bytes, 4 cols per u32
    __shared__ int      segsum[NSEG * RPB];
    __shared__ float    partial[NSEG * RPB];

    const int tid   = threadIdx.x;
    const int seg   = tid >> 6;
    const int lane  = tid & 63;
    const int rowbb = blockIdx.x * (RPB * TPB2);

    // prologue: stage tile 0 into buf 0 (coalesced nt int4 load + byte-pack)
    {
        const iv4* tile = (const iv4*)(x + (size_t)rowbb * NN);
        #pragma unroll
        for (int j = 0; j < 16; ++j) {
            int i = tid + BLK * j;
            iv4 a = __builtin_nontemporal_load(&tile[i]);
            unsigned m = (unsigned)(a.x & 1) | ((unsigned)(a.y & 1) << 8)
                       | ((unsigned)(a.z & 1) << 16) | ((unsigned)(a.w & 1) << 24);
            xb[0][(i >> 7) * XSTR + (i & 127)] = m;
        }
    }
    __syncthreads();

    int cur = 0;
    iv4 S[16];
    #pragma unroll
    for (int t = 0; t < TPB2; ++t) {
        const int row0 = rowbb + t * RPB;

        // issue next tile's global loads (consumed only after the gathers)
        if (t + 1 < TPB2) {
            const iv4* tile = (const iv4*)(x + (size_t)(row0 + RPB) * NN);
            #pragma unroll
            for (int j = 0; j < 16; ++j) S[j] = __builtin_nontemporal_load(&tile[tid + BLK * j]);
        }

        // own-segment words + segment sum
        unsigned w[16];
        int ssum = 0;
        #pragma unroll
        for (int m = 0; m < 16; ++m) {
            w[m] = xb[cur][lane * XSTR + seg * 16 + m];   // stride 129 -> conflict-free
            ssum += __popc(w[m]);                         // bytes are 0x00/0x01
        }
        segsum[seg * 64 + lane] = ssum;
        __syncthreads();

        int g = 0, gtot = 0;
        #pragma unroll
        for (int s = 0; s < NSEG; ++s) {
            int v = segsum[s * 64 + lane];
            if (s < seg) g += v;
            gtot += v;
        }

        // gathers: u32 per (t,g); select bf16 half by x-bit, <<16 bit-cast to f32
        float a0 = 0.f, a1 = 0.f, a2 = 0.f, a3 = 0.f;
        const unsigned* Tseg = T16 + (size_t)(seg * SEGW) * T16STR;
        #pragma unroll
        for (int m = 0; m < 16; ++m) {
            const unsigned* Tm = Tseg + (size_t)(4 * m) * T16STR;
            unsigned wm = w[m];
            int b0 = wm & 1;         g += b0; unsigned u0 = Tm[0 * T16STR + g];
            a0 += __uint_as_float(b0 ? (u0 & 0xffff0000u) : (u0 << 16));
            int b1 = (wm >> 8)  & 1; g += b1; unsigned u1 = Tm[1 * T16STR + g];
            a1 += __uint_as_float(b1 ? (u1 & 0xffff0000u) : (u1 << 16));
            int b2 = (wm >> 16) & 1; g += b2; unsigned u2 = Tm[2 * T16STR + g];
            a2 += __uint_as_float(b2 ? (u2 & 0xffff0000u) : (u2 << 16));
            int b3 = (wm >> 24) & 1; g += b3; unsigned u3 = Tm[3 * T16STR + g];
            a3 += __uint_as_float(b3 ? (u3 & 0xffff0000u) : (u3 << 16));
        }
        partial[seg * 64 + lane] = (a0 + a1) + (a2 + a3);

        // now pack+write the prefetched tile into the other buffer
        if (t + 1 < TPB2) {
            #pragma unroll
            for (int j = 0; j < 16; ++j) {
                int i = tid + BLK * j;
                unsigned m = (unsigned)(S[j].x & 1) | ((unsigned)(S[j].y & 1) << 8)
                           | ((unsigned)(S[j].z & 1) << 16) | ((unsigned)(S[j].w & 1) << 24);
                xb[cur ^ 1][(i >> 7) * XSTR + (i & 127)] = m;
            }
        }
        __syncthreads();   // partial ready AND next buffer staged

        if (seg == 0) {
            float s = logE[gtot];
            #pragma unroll
            for (int q = 0; q < NSEG; ++q) s += partial[q * 64 + lane];
            out[row0 + lane] = s;
        }
        cur ^= 1;
    }
}

extern "C" void kernel_launch(void* const* d_in, const int* in_sizes, int n_in,
                              void* d_out, int out_size, void* d_ws, size_t ws_size,
                              hipStream_t stream)
{
    const int*   x    = (const int*)d_in[0];
    const float* W    = (const float*)d_in[1];
    const float* endW = (const float*)d_in[2];
    float*       out  = (float*)d_out;

    unsigned* T16  = (unsigned*)d_ws;                               // 512*528*4 = 1,081,344 B
    float*    logE = (float*)((char*)d_ws + (size_t)TROWS * T16STR * sizeof(unsigned));

    {
        int total  = TROWS * TCOLS;
        int blocks = (total + 255) / 256;
        build_table_kernel<<<blocks, 256, 0, stream>>>(W, T16);
    }
    build_endw_kernel<<<1, 64, 0, stream>>>(endW, logE);
    pc_main_kernel<<<BB / (RPB * TPB2), BLK, 0, stream>>>(x, T16, logE, out);
}

// Round 9
// 201.665 us; speedup vs baseline: 1.0946x; 1.0946x over previous
//
#include <hip/hip_runtime.h>
#include <math.h>

#define NN      512     // N (columns of x)
#define KK      513     // K
#define BB      65536   // batch
#define TROWS   512     // table rows, t = 0..511
#define TCOLS   513     // table cols, g = 0..512
#define T16STR  528     // u32 stride per table row (2112 B, 64B-aligned)

#define RPB     64            // rows per block
#define NSEG    8             // segments per row
#define SEGW    64            // columns per segment
#define BLK     (RPB * NSEG)  // 512 threads = 8 waves
#define XSTR    129           // LDS row stride in u32 (128 + 1 pad: conflict-free both phases)

typedef int iv4 __attribute__((ext_vector_type(4)));

__device__ __forceinline__ unsigned f2bf(float f) {   // RNE f32 -> bf16 (finite only)
    unsigned u = __float_as_uint(f);
    return (u + 0x7fffu + ((u >> 16) & 1u)) >> 16;
}

// T16[t*T16STR + g] = pack(bf16 logsm(c=0), bf16 logsm(c=1)); edges/unreachable = 0 (log 1)
__global__ void build_table_kernel(const float* __restrict__ W, unsigned* __restrict__ T16) {
    int idx = blockIdx.x * blockDim.x + threadIdx.x;
    if (idx >= TROWS * TCOLS) return;
    int t = idx / TCOLS;
    int g = idx - t * TCOLS;
    float v0 = 0.f, v1 = 0.f;
    if (t >= 1 && g >= 1 && g <= t) {
        const float* w = W + ((size_t)(t - 1) * (KK - 1) + (g - 1)) * 2;
        float w0 = w[0], w1 = w[1];
        float m  = fmaxf(w0, w1);
        float lse = m + logf(expf(w0 - m) + expf(w1 - m));
        v0 = w0 - lse;
        v1 = w1 - lse;
    }
    T16[t * T16STR + g] = f2bf(v0) | (f2bf(v1) << 16);
}

// logE[k] = endW[k] - logsumexp(endW)   (513 entries, f32), one wave
__global__ void build_endw_kernel(const float* __restrict__ endW, float* __restrict__ logE) {
    int lane = threadIdx.x;  // 0..63
    float vals[9];
    float m = -1e30f;
    #pragma unroll
    for (int k = 0; k < 9; ++k) {
        int i = lane + 64 * k;
        vals[k] = (i < KK) ? endW[i] : -1e30f;
        m = fmaxf(m, vals[k]);
    }
    #pragma unroll
    for (int d = 32; d >= 1; d >>= 1) m = fmaxf(m, __shfl_xor(m, d, 64));
    float s = 0.f;
    #pragma unroll
    for (int k = 0; k < 9; ++k) s += expf(vals[k] - m);
    #pragma unroll
    for (int d = 32; d >= 1; d >>= 1) s += __shfl_xor(s, d, 64);
    float lse = m + logf(s);
    #pragma unroll
    for (int k = 0; k < 9; ++k) {
        int i = lane + 64 * k;
        if (i < KK) logE[i] = endW[i] - lse;
    }
}

// R6 structure (4 blocks/CU, cross-block TLP hides gather TA under the HBM
// stream) + bf16-packed table (halves lines per gather instruction).
// Block = 512 threads = 64 rows x 8 segments (wave i = segment i).
__global__ __launch_bounds__(BLK, 8) void pc_main_kernel(
    const int* __restrict__ x, const unsigned* __restrict__ T16,
    const float* __restrict__ logE, float* __restrict__ out)
{
    __shared__ unsigned xb[RPB * XSTR];        // packed 0/1 bytes, 4 cols per u32
    __shared__ int      segsum[NSEG * RPB];
    __shared__ float    partial[NSEG * RPB];

    const int tid  = threadIdx.x;
    const int row0 = blockIdx.x * RPB;

    // ---- phase 1: coalesced nt load + byte-pack into LDS ----
    {
        const iv4* tile = (const iv4*)(x + (size_t)row0 * NN);  // 8192 int4, linear
        #pragma unroll
        for (int j = 0; j < 16; ++j) {
            int i = tid + BLK * j;            // lane-consecutive -> minimal TA lines
            iv4 a = __builtin_nontemporal_load(&tile[i]);
            unsigned m = (unsigned)(a.x & 1) | ((unsigned)(a.y & 1) << 8)
                       | ((unsigned)(a.z & 1) << 16) | ((unsigned)(a.w & 1) << 24);
            xb[(i >> 7) * XSTR + (i & 127)] = m;
        }
    }
    __syncthreads();

    // ---- phase 2: own-segment words + segment sums ----
    const int seg  = tid >> 6;    // wave index = segment
    const int lane = tid & 63;    // row within block

    unsigned w[16];
    int ssum = 0;
    #pragma unroll
    for (int m = 0; m < 16; ++m) {
        w[m] = xb[lane * XSTR + seg * 16 + m];   // stride 129 -> conflict-free
        ssum += __popc(w[m]);                    // bytes are 0x00/0x01
    }
    segsum[seg * 64 + lane] = ssum;
    __syncthreads();

    int g = 0, gtot = 0;
    #pragma unroll
    for (int s = 0; s < NSEG; ++s) {
        int v = segsum[s * 64 + lane];
        if (s < seg) g += v;
        gtot += v;
    }

    // ---- phase 3: bf16-table gathers (one table row per wave-instr) ----
    float a0 = 0.f, a1 = 0.f, a2 = 0.f, a3 = 0.f;
    const unsigned* Tseg = T16 + (size_t)(seg * SEGW) * T16STR;
    #pragma unroll
    for (int m = 0; m < 16; ++m) {
        const unsigned* Tm = Tseg + (size_t)(4 * m) * T16STR;
        unsigned wm = w[m];
        int b0 = wm & 1;         g += b0; unsigned u0 = Tm[0 * T16STR + g];
        a0 += __uint_as_float(b0 ? (u0 & 0xffff0000u) : (u0 << 16));
        int b1 = (wm >> 8)  & 1; g += b1; unsigned u1 = Tm[1 * T16STR + g];
        a1 += __uint_as_float(b1 ? (u1 & 0xffff0000u) : (u1 << 16));
        int b2 = (wm >> 16) & 1; g += b2; unsigned u2 = Tm[2 * T16STR + g];
        a2 += __uint_as_float(b2 ? (u2 & 0xffff0000u) : (u2 << 16));
        int b3 = (wm >> 24) & 1; g += b3; unsigned u3 = Tm[3 * T16STR + g];
        a3 += __uint_as_float(b3 ? (u3 & 0xffff0000u) : (u3 << 16));
    }
    partial[seg * 64 + lane] = (a0 + a1) + (a2 + a3);
    __syncthreads();

    // ---- phase 4: per-row reduction (wave 0 only) ----
    if (seg == 0) {
        float s = logE[gtot];
        #pragma unroll
        for (int t = 0; t < NSEG; ++t) s += partial[t * 64 + lane];
        out[row0 + lane] = s;
    }
}

extern "C" void kernel_launch(void* const* d_in, const int* in_sizes, int n_in,
                              void* d_out, int out_size, void* d_ws, size_t ws_size,
                              hipStream_t stream)
{
    const int*   x    = (const int*)d_in[0];
    const float* W    = (const float*)d_in[1];
    const float* endW = (const float*)d_in[2];
    float*       out  = (float*)d_out;

    unsigned* T16  = (unsigned*)d_ws;                               // 512*528*4 = 1,081,344 B
    float*    logE = (float*)((char*)d_ws + (size_t)TROWS * T16STR * sizeof(unsigned));

    {
        int total  = TROWS * TCOLS;
        int blocks = (total + 255) / 256;
        build_table_kernel<<<blocks, 256, 0, stream>>>(W, T16);
    }
    build_endw_kernel<<<1, 64, 0, stream>>>(endW, logE);
    pc_main_kernel<<<BB / RPB, BLK, 0, stream>>>(x, T16, logE, out);
}